// Round 8
// baseline (2213.587 us; speedup 1.0000x reference)
//
#include <hip/hip_runtime.h>

#define EMBD 256
#define HIDD 512
#define SEQL 512
#define NRNG 8            // rings of 16 batch rows
#define THR  256

typedef unsigned int u32;
typedef unsigned long long u64;
typedef _Float16 half8 __attribute__((ext_vector_type(8)));
typedef _Float16 half2v __attribute__((ext_vector_type(2)));
typedef float f32x4 __attribute__((ext_vector_type(4)));

#define WS_WA_OFF 0          // 786432 B  (W as A-fragments, f16-packed)
#define WS_X_OFF  786432     // u64 X[2 slots][8 rings][16 rows][256 pairs] = 512 KB
// exchange u64 = (tag << 32) | (2 packed f16 state cols)

static __device__ __forceinline__ u32 packh2(float a, float b) {
    _Float16 lo = (_Float16)a, hi = (_Float16)b;
    return (u32)__builtin_bit_cast(unsigned short, lo)
         | ((u32)__builtin_bit_cast(unsigned short, hi) << 16);
}

// zero X (both slots): 65536 u64, grid 64 x 1024
__global__ __launch_bounds__(1024)
void init_X(u64* __restrict__ X) {
    X[(size_t)blockIdx.x * 1024 + threadIdx.x] = 0ull;
}

// Pack W (f32 [768][512]) into A-fragments for mfma_f32_16x16x32_f16.
// A = W^T: m = hidden col, k = input dim. Frag for (cg,mt,chunk c):
// lane l, dword d holds f16 pair (k0, k0+1), k0 = 32c + 8*(l>>4) + 2d,
// at hcol = cg*64 + mt*16 + (l&15).  Grid 768 x 256.
__global__ __launch_bounds__(256)
void convert_WA(const float* __restrict__ W, u32* __restrict__ WA) {
    const int b = blockIdx.x;                 // (cg*4+mt)*24 + c
    const int c = b % 24, mtcg = b / 24;
    const int mt = mtcg & 3, cg = mtcg >> 2;
    const int tid = threadIdx.x, l = tid >> 2, d = tid & 3;
    const int k0 = 32 * c + 8 * (l >> 4) + 2 * d;
    const int hc = cg * 64 + mt * 16 + (l & 15);
    WA[b * 256 + tid] = packh2(W[(size_t)k0 * HIDD + hc],
                               W[(size_t)(k0 + 1) * HIDD + hc]);
}

// 64 WGs x 256 thr. WG (ring, cg): ring's 16 rows x cols [cg*64,+64).
// Wave w (0..3): k-quarter = emb chunks {2w,2w+1} + state chunks {4w..4w+3}
// (state producers {2w,2w+1}); computes all 4 M-tiles (64 cols) for its k.
// B-frags (state) ARE the exchange u64s: no LDS/readlane broadcast path.
__global__ __launch_bounds__(THR, 1)
void rnn_mfma(const int*   __restrict__ tokens,
              const float* __restrict__ V,
              const u32*   __restrict__ WA,
              const float* __restrict__ bias,
              const float* __restrict__ Wd,
              const float* __restrict__ bd,
              float*       __restrict__ y,
              u64*         __restrict__ X)
{
    __shared__ f32x4 P[4][4][64];     // [writer wave][mt][lane] partials, 16 KB
    __shared__ float yp[16][17];

    const int tid  = threadIdx.x;
    const int wg   = blockIdx.x;
    const int ring = wg >> 3, cg = wg & 7;
    const int w    = tid >> 6, l = tid & 63;
    const int grp  = l >> 4, mrow = l & 15;   // B-frag: n=row=mrow, k-group=grp
    const int growbase = ring * 16;

    // W A-frags into registers: 4 mt x 6 chunks x 4 dwords = 96 VGPR
    uint4 wa[4][6];
    #pragma unroll
    for (int mt = 0; mt < 4; ++mt)
        #pragma unroll
        for (int j = 0; j < 6; ++j) {
            const int gc = (j < 2) ? (2 * w + j) : (8 + 4 * w + (j - 2));
            wa[mt][j] = *(const uint4*)&WA[(((cg * 4 + mt) * 24 + gc) * 64 + l) * 4];
        }

    // reduce-role constants: thread -> (mt2, lane l2) of the D layout
    const int mt2 = tid >> 6, l2 = tid & 63, g2 = l2 >> 4, row2 = l2 & 15;
    const float4 bias4 = *(const float4*)&bias[cg * 64 + mt2 * 16 + 4 * g2];

    // emb prefetch for t=0 (per-lane, row mrow, this wave's 2 emb chunks)
    const int erow = growbase + mrow;
    float4 eA0, eB0, eA1, eB1;
    {
        const int tok = tokens[erow * SEQL + 0];
        const float* vb = V + (size_t)tok * EMBD;
        eA0 = *(const float4*)&vb[32 * (2 * w)     + 8 * grp];
        eB0 = *(const float4*)&vb[32 * (2 * w)     + 8 * grp + 4];
        eA1 = *(const float4*)&vb[32 * (2 * w + 1) + 8 * grp];
        eB1 = *(const float4*)&vb[32 * (2 * w + 1) + 8 * grp + 4];
    }

    for (int t = 0; t < SEQL; ++t) {
        // ---- speculative state loads: state(t-1), tag t, slot (t+1)&1 ----
        const u64* Xr = X + (((size_t)((t + 1) & 1) * NRNG + ring) * 16 + mrow) * 256;
        u64 sv[16];
        #pragma unroll
        for (int j = 0; j < 4; ++j) {
            const int p0 = 16 * (4 * w + j) + 4 * grp;
            #pragma unroll
            for (int d = 0; d < 4; ++d)
                sv[j * 4 + d] = __hip_atomic_load(Xr + p0 + d,
                                    __ATOMIC_RELAXED, __HIP_MEMORY_SCOPE_AGENT);
        }

        // ---- emb frags for step t (from prefetched f32) ----
        uint4 eb0, eb1;
        eb0.x = packh2(eA0.x, eA0.y); eb0.y = packh2(eA0.z, eA0.w);
        eb0.z = packh2(eB0.x, eB0.y); eb0.w = packh2(eB0.z, eB0.w);
        eb1.x = packh2(eA1.x, eA1.y); eb1.y = packh2(eA1.z, eA1.w);
        eb1.z = packh2(eB1.x, eB1.y); eb1.w = packh2(eB1.z, eB1.w);

        // ---- prefetch emb for t+1 (recurrence-independent) ----
        {
            const int tn = (t + 1 < SEQL) ? (t + 1) : (SEQL - 1);
            const int tok = tokens[erow * SEQL + tn];
            const float* vb = V + (size_t)tok * EMBD;
            eA0 = *(const float4*)&vb[32 * (2 * w)     + 8 * grp];
            eB0 = *(const float4*)&vb[32 * (2 * w)     + 8 * grp + 4];
            eA1 = *(const float4*)&vb[32 * (2 * w + 1) + 8 * grp];
            eB1 = *(const float4*)&vb[32 * (2 * w + 1) + 8 * grp + 4];
        }

        f32x4 acc[4];
        #pragma unroll
        for (int mt = 0; mt < 4; ++mt) acc[mt] = (f32x4){0.f, 0.f, 0.f, 0.f};

        // ---- emb MFMAs (run while state loads are in flight) ----
        #pragma unroll
        for (int mt = 0; mt < 4; ++mt) {
            acc[mt] = __builtin_amdgcn_mfma_f32_16x16x32_f16(
                __builtin_bit_cast(half8, wa[mt][0]), __builtin_bit_cast(half8, eb0),
                acc[mt], 0, 0, 0);
            acc[mt] = __builtin_amdgcn_mfma_f32_16x16x32_f16(
                __builtin_bit_cast(half8, wa[mt][1]), __builtin_bit_cast(half8, eb1),
                acc[mt], 0, 0, 0);
        }

        // ---- validate embedded tags (retry on speculation miss) ----
        {
            bool ok = true;
            #pragma unroll
            for (int i = 0; i < 16; ++i) ok &= ((u32)(sv[i] >> 32) == (u32)t);
            while (!__all(ok)) {
                __builtin_amdgcn_s_sleep(1);
                #pragma unroll
                for (int j = 0; j < 4; ++j) {
                    const int p0 = 16 * (4 * w + j) + 4 * grp;
                    #pragma unroll
                    for (int d = 0; d < 4; ++d)
                        sv[j * 4 + d] = __hip_atomic_load(Xr + p0 + d,
                                            __ATOMIC_RELAXED, __HIP_MEMORY_SCOPE_AGENT);
                }
                ok = true;
                #pragma unroll
                for (int i = 0; i < 16; ++i) ok &= ((u32)(sv[i] >> 32) == (u32)t);
            }
        }

        // ---- state MFMAs: exchange u64 lows ARE the B-frags ----
        #pragma unroll
        for (int j = 0; j < 4; ++j) {
            uint4 bf;
            bf.x = (u32)sv[j * 4 + 0]; bf.y = (u32)sv[j * 4 + 1];
            bf.z = (u32)sv[j * 4 + 2]; bf.w = (u32)sv[j * 4 + 3];
            #pragma unroll
            for (int mt = 0; mt < 4; ++mt)
                acc[mt] = __builtin_amdgcn_mfma_f32_16x16x32_f16(
                    __builtin_bit_cast(half8, wa[mt][2 + j]), __builtin_bit_cast(half8, bf),
                    acc[mt], 0, 0, 0);
        }

        // ---- K-reduce across 4 waves via LDS ----
        #pragma unroll
        for (int mt = 0; mt < 4; ++mt) P[w][mt][l] = acc[mt];
        __syncthreads();   // B1

        {
            f32x4 s = P[0][mt2][l2];
            s += P[1][mt2][l2];
            s += P[2][mt2][l2];
            s += P[3][mt2][l2];
            const float s0 = tanhf(s.x + bias4.x);
            const float s1 = tanhf(s.y + bias4.y);
            const float s2 = tanhf(s.z + bias4.z);
            const float s3 = tanhf(s.w + bias4.w);
            // D layout: row=n=l2&15, hcols m = mt2*16 + 4*g2 + {0..3} (consecutive)
            const u32 d0 = packh2(s0, s1), d1 = packh2(s2, s3);
            const u64 tag = (u64)(u32)(t + 1) << 32;
            u64* dst = X + (((size_t)(t & 1) * NRNG + ring) * 16 + row2) * 256
                         + (cg * 32 + mt2 * 8 + 2 * g2);
            __hip_atomic_store(dst,     tag | d0, __ATOMIC_RELAXED, __HIP_MEMORY_SCOPE_AGENT);
            __hip_atomic_store(dst + 1, tag | d1, __ATOMIC_RELAXED, __HIP_MEMORY_SCOPE_AGENT);
        }
        __syncthreads();   // B2: protect P before next iteration
    }

    // ---- epilogue: cg==0 WG of each ring computes y for its 16 rows ----
    if (cg == 0) {
        const int row = tid >> 4, q = tid & 15;
        const u64* Xr = X + (((size_t)1 * NRNG + ring) * 16 + row) * 256 + q * 16;
        u64 vv[16];
        for (;;) {
            bool ok = true;
            #pragma unroll
            for (int i = 0; i < 16; ++i) {
                vv[i] = __hip_atomic_load(Xr + i, __ATOMIC_RELAXED, __HIP_MEMORY_SCOPE_AGENT);
                ok &= ((u32)(vv[i] >> 32) == (u32)SEQL);
            }
            if (__all(ok)) break;
            __builtin_amdgcn_s_sleep(1);
        }
        float accy = 0.f;
        #pragma unroll
        for (int i = 0; i < 16; ++i) {
            const int p = q * 16 + i;
            const float2 wd = *(const float2*)&Wd[2 * p];
            const half2v hv = __builtin_bit_cast(half2v, (u32)vv[i]);
            accy += (float)hv.x * wd.x + (float)hv.y * wd.y;
        }
        yp[row][q] = accy;
        __syncthreads();
        if (tid < 16) {
            float s = 0.f;
            #pragma unroll
            for (int j = 0; j < 16; ++j) s += yp[tid][j];
            y[growbase + tid] = s + bd[0];
        }
    }
}

extern "C" void kernel_launch(void* const* d_in, const int* in_sizes, int n_in,
                              void* d_out, int out_size, void* d_ws, size_t ws_size,
                              hipStream_t stream)
{
    const int*   tokens = (const int*)  d_in[0];
    const float* V      = (const float*)d_in[1];
    const float* W      = (const float*)d_in[2];
    const float* b      = (const float*)d_in[3];
    const float* Wd     = (const float*)d_in[4];
    const float* bd     = (const float*)d_in[5];
    float* y = (float*)d_out;

    u32* WA = (u32*)((char*)d_ws + WS_WA_OFF);
    u64* X  = (u64*)((char*)d_ws + WS_X_OFF);

    hipLaunchKernelGGL(init_X, dim3(64), dim3(1024), 0, stream, X);
    hipLaunchKernelGGL(convert_WA, dim3(768), dim3(256), 0, stream, W, WA);
    hipLaunchKernelGGL(rnn_mfma, dim3(64), dim3(THR), 0, stream,
                       tokens, V, WA, b, Wd, bd, y, X);
}

// Round 10
// 2084.289 us; speedup vs baseline: 1.0620x; 1.0620x over previous
//
#include <hip/hip_runtime.h>

#define EMBD 256
#define HIDD 512
#define SEQL 512
#define NRNG 8            // rings of 16 batch rows
#define THR  256
#define SPIN_CAP 16384

typedef unsigned int u32;
typedef unsigned long long u64;
typedef _Float16 half8 __attribute__((ext_vector_type(8)));
typedef _Float16 h2 __attribute__((ext_vector_type(2)));
typedef float f32x4 __attribute__((ext_vector_type(4)));

#define WS_WA_OFF 0          // 786432 B : W frags [mt 0..31][chunk 0..23][64 lanes][4 dw]
#define WS_X_OFF  786432     // 524288 B : u64 X[2 slots][8 rings][16 rows][256 pairs]
// total ws use: 1.25 MiB (same class as all passing rounds)

static __device__ __forceinline__ u32 packh2(float a, float b) {
    _Float16 lo = (_Float16)a, hi = (_Float16)b;
    return (u32)__builtin_bit_cast(unsigned short, lo)
         | ((u32)__builtin_bit_cast(unsigned short, hi) << 16);
}

__global__ __launch_bounds__(1024)
void init_X(u64* __restrict__ X) {
    X[(size_t)blockIdx.x * 1024 + threadIdx.x] = 0ull;   // grid 64 -> 65536 u64
}

// W (f32 [768][512]) -> A-frags for mfma_f32_16x16x32_f16.
// Frag (mt, c): lane l, dword d = f16 pair (k0,k0+1), k0 = 32c + 8*(l>>4) + 2d,
// hcol = mt*16 + (l&15). Grid 768 (= mt*24+c) x 256.
__global__ __launch_bounds__(256)
void convert_WA(const float* __restrict__ W, u32* __restrict__ WA) {
    const int b = blockIdx.x;
    const int mt = b / 24, c = b % 24;
    const int tid = threadIdx.x, l = tid >> 2, d = tid & 3;
    const int k0 = 32 * c + 8 * (l >> 4) + 2 * d;
    const int hc = mt * 16 + (l & 15);
    WA[b * 256 + tid] = packh2(W[(size_t)k0 * HIDD + hc],
                               W[(size_t)(k0 + 1) * HIDD + hc]);
}

// 64 WGs (ring 0..7, cg 0..7) x 256 thr (4 waves). Wave w: mt = cg*4+w (16 cols),
// FULL K=768; stages state chunks {4w..4w+3}. Emb staged as B-frags in LDS,
// loaded one step ahead. One barrier/step. Tag-embedded depth-2 exchange.
__global__ __launch_bounds__(THR, 1)
void rnn_v10(const int*   __restrict__ tokens,
             const float* __restrict__ V,
             const u32*   __restrict__ WA,
             const float* __restrict__ bias,
             const float* __restrict__ Wd,
             const float* __restrict__ bd,
             float*       __restrict__ y,
             u64*         __restrict__ X)
{
    __shared__ uint4 Sst[2][16][64];   // state B-frags, 32 KB
    __shared__ uint4 Sem[2][8][64];    // emb   B-frags, 16 KB
    __shared__ int   tk[16][SEQL];     // tokens, 32 KB
    __shared__ float yp[16][17];

    const int tid  = threadIdx.x;
    const int wg   = blockIdx.x;
    const int ring = wg >> 3, cg = wg & 7;
    const int w    = tid >> 6, l = tid & 63;
    const int g    = l >> 4, row = l & 15;
    const int mt   = cg * 4 + w;

    // stage tokens for our 16 rows
    for (int i = tid; i < 16 * SEQL; i += THR)
        tk[i >> 9][i & 511] = tokens[(ring * 16 + (i >> 9)) * SEQL + (i & 511)];

    // W frags: 24 chunks x 4 dwords = 96 VGPR
    uint4 wa[24];
    #pragma unroll
    for (int c = 0; c < 24; ++c)
        wa[c] = *(const uint4*)&WA[((mt * 24 + c) * 64 + l) * 4];

    const float4 bias4 = *(const float4*)&bias[mt * 16 + 4 * g];

    // emb staging roles: entries tid and tid+256 of the 512-entry frag buffer
    const int c0 = tid >> 6,        l0 = tid & 63,  g0 = l0 >> 4, r0 = l0 & 15;
    const int c1 = (tid + 256) >> 6, l1 = l0,       g1 = g0,      r1 = r0;

    __syncthreads();   // tokens visible

    // prologue: emb frags for t=0 -> Sem[0]
    float4 ea0, ea1, eb0, eb1;
    {
        const float* p0 = V + (size_t)tk[r0][0] * EMBD + 32 * c0 + 8 * g0;
        const float* p1 = V + (size_t)tk[r1][0] * EMBD + 32 * c1 + 8 * g1;
        ea0 = *(const float4*)p0; ea1 = *(const float4*)(p0 + 4);
        eb0 = *(const float4*)p1; eb1 = *(const float4*)(p1 + 4);
        Sem[0][c0][l0] = (uint4){packh2(ea0.x, ea0.y), packh2(ea0.z, ea0.w),
                                 packh2(ea1.x, ea1.y), packh2(ea1.z, ea1.w)};
        Sem[0][c1][l1] = (uint4){packh2(eb0.x, eb0.y), packh2(eb0.z, eb0.w),
                                 packh2(eb1.x, eb1.y), packh2(eb1.z, eb1.w)};
    }
    __syncthreads();   // B0

    for (int t = 0; t < SEQL; ++t) {
        const int slot_r = (t + 1) & 1;   // read state(t-1) + write emb(t+1)
        const int slot_w = t & 1;         // compute buffers + state(t) stores

        // ---- (1) issue V loads for emb(t+1) (independent of recurrence) ----
        const int tn = (t + 1 < SEQL) ? (t + 1) : (SEQL - 1);
        {
            const float* p0 = V + (size_t)tk[r0][tn] * EMBD + 32 * c0 + 8 * g0;
            const float* p1 = V + (size_t)tk[r1][tn] * EMBD + 32 * c1 + 8 * g1;
            ea0 = *(const float4*)p0; ea1 = *(const float4*)(p0 + 4);
            eb0 = *(const float4*)p1; eb1 = *(const float4*)(p1 + 4);
        }

        // ---- (2) state stage: chunks 4w..4w+3, tag t, bounded validate ----
        const u64* Xr = X + (((size_t)slot_r * NRNG + ring) * 16 + row) * 256;
        u64 sv[16];
        #pragma unroll
        for (int j = 0; j < 4; ++j) {
            const int p = (4 * w + j) * 16 + 4 * g;
            #pragma unroll
            for (int d = 0; d < 4; ++d)
                sv[4 * j + d] = __hip_atomic_load(Xr + p + d,
                                    __ATOMIC_RELAXED, __HIP_MEMORY_SCOPE_AGENT);
        }
        {
            bool ok = true;
            #pragma unroll
            for (int i = 0; i < 16; ++i) ok &= ((u32)(sv[i] >> 32) == (u32)t);
            int guard = 0;
            while (!__all(ok) && guard < SPIN_CAP) {
                ++guard;
                __builtin_amdgcn_s_sleep(1);
                #pragma unroll
                for (int j = 0; j < 4; ++j) {
                    const int p = (4 * w + j) * 16 + 4 * g;
                    #pragma unroll
                    for (int d = 0; d < 4; ++d)
                        sv[4 * j + d] = __hip_atomic_load(Xr + p + d,
                                            __ATOMIC_RELAXED, __HIP_MEMORY_SCOPE_AGENT);
                }
                ok = true;
                #pragma unroll
                for (int i = 0; i < 16; ++i) ok &= ((u32)(sv[i] >> 32) == (u32)t);
            }
        }
        #pragma unroll
        for (int j = 0; j < 4; ++j)
            Sst[slot_w][4 * w + j][l] = (uint4){(u32)sv[4 * j + 0], (u32)sv[4 * j + 1],
                                                (u32)sv[4 * j + 2], (u32)sv[4 * j + 3]};
        __syncthreads();   // B1: all 24 frag buffers for step t ready

        // ---- (4) emb(t+1) pack + write (double-buffered; race-free per B1) ----
        Sem[slot_r][c0][l0] = (uint4){packh2(ea0.x, ea0.y), packh2(ea0.z, ea0.w),
                                      packh2(ea1.x, ea1.y), packh2(ea1.z, ea1.w)};
        Sem[slot_r][c1][l1] = (uint4){packh2(eb0.x, eb0.y), packh2(eb0.z, eb0.w),
                                      packh2(eb1.x, eb1.y), packh2(eb1.z, eb1.w)};

        // ---- (5) MFMA: 24 chunks, 4 round-robin acc chains ----
        f32x4 ac0 = (f32x4){0.f,0.f,0.f,0.f}, ac1 = ac0, ac2 = ac0, ac3 = ac0;
        #pragma unroll
        for (int c = 0; c < 8; ++c) {
            const uint4 B = Sem[slot_w][c][l];
            f32x4& a = (c & 3) == 0 ? ac0 : (c & 3) == 1 ? ac1 : (c & 3) == 2 ? ac2 : ac3;
            a = __builtin_amdgcn_mfma_f32_16x16x32_f16(
                    __builtin_bit_cast(half8, wa[c]), __builtin_bit_cast(half8, B), a, 0, 0, 0);
        }
        #pragma unroll
        for (int c = 0; c < 16; ++c) {
            const uint4 B = Sst[slot_w][c][l];
            f32x4& a = (c & 3) == 0 ? ac0 : (c & 3) == 1 ? ac1 : (c & 3) == 2 ? ac2 : ac3;
            a = __builtin_amdgcn_mfma_f32_16x16x32_f16(
                    __builtin_bit_cast(half8, wa[8 + c]), __builtin_bit_cast(half8, B), a, 0, 0, 0);
        }
        const f32x4 s = (ac0 + ac1) + (ac2 + ac3);

        // ---- (6) bias + tanh + pack + tagged stores ----
        {
            const float t0 = tanhf(s.x + bias4.x);
            const float t1 = tanhf(s.y + bias4.y);
            const float t2 = tanhf(s.z + bias4.z);
            const float t3 = tanhf(s.w + bias4.w);
            const u64 tag = (u64)(u32)(t + 1) << 32;
            u64* dst = X + (((size_t)slot_w * NRNG + ring) * 16 + row) * 256 + mt * 8 + 2 * g;
            __hip_atomic_store(dst,     tag | packh2(t0, t1),
                               __ATOMIC_RELAXED, __HIP_MEMORY_SCOPE_AGENT);
            __hip_atomic_store(dst + 1, tag | packh2(t2, t3),
                               __ATOMIC_RELAXED, __HIP_MEMORY_SCOPE_AGENT);
        }
    }

    // ---- epilogue: cg==0 WG per ring: y = state(511) . Wd + bd ----
    if (cg == 0) {
        const int r2 = tid >> 4, q = tid & 15;
        const u64* Xe = X + (((size_t)1 * NRNG + ring) * 16 + r2) * 256 + q * 16;
        u64 vv[16];
        bool ok;
        int guard = 0;
        do {
            #pragma unroll
            for (int i = 0; i < 16; ++i)
                vv[i] = __hip_atomic_load(Xe + i, __ATOMIC_RELAXED, __HIP_MEMORY_SCOPE_AGENT);
            ok = true;
            #pragma unroll
            for (int i = 0; i < 16; ++i) ok &= ((u32)(vv[i] >> 32) == (u32)SEQL);
            if (__all(ok)) break;
            __builtin_amdgcn_s_sleep(1);
        } while (++guard < SPIN_CAP);
        float accy = 0.f;
        #pragma unroll
        for (int i = 0; i < 16; ++i) {
            const int p = q * 16 + i;
            const float2 wd = *(const float2*)&Wd[2 * p];
            const h2 hv = __builtin_bit_cast(h2, (u32)vv[i]);
            accy += (float)hv.x * wd.x + (float)hv.y * wd.y;
        }
        yp[r2][q] = accy;
        __syncthreads();
        if (tid < 16) {
            float sy = 0.f;
            #pragma unroll
            for (int j = 0; j < 16; ++j) sy += yp[tid][j];
            y[ring * 16 + tid] = sy + bd[0];
        }
    }
}

extern "C" void kernel_launch(void* const* d_in, const int* in_sizes, int n_in,
                              void* d_out, int out_size, void* d_ws, size_t ws_size,
                              hipStream_t stream)
{
    const int*   tokens = (const int*)  d_in[0];
    const float* V      = (const float*)d_in[1];
    const float* W      = (const float*)d_in[2];
    const float* b      = (const float*)d_in[3];
    const float* Wd     = (const float*)d_in[4];
    const float* bd     = (const float*)d_in[5];
    float* y = (float*)d_out;

    u32* WA = (u32*)((char*)d_ws + WS_WA_OFF);
    u64* X  = (u64*)((char*)d_ws + WS_X_OFF);

    hipLaunchKernelGGL(init_X, dim3(64), dim3(1024), 0, stream, X);
    hipLaunchKernelGGL(convert_WA, dim3(768), dim3(256), 0, stream, W, WA);
    hipLaunchKernelGGL(rnn_v10, dim3(64), dim3(THR), 0, stream,
                       tokens, V, WA, b, Wd, bd, y, X);
}